// Round 5
// baseline (386.129 us; speedup 1.0000x reference)
//
#include <hip/hip_runtime.h>
#include <math.h>

// ProbAttention (Informer ProbSparse) — B=8 L=2048 H=8 D=64 u=40
// q/k/v reshape(B,H,L,D) is a flat reinterpretation -> treat as (BH=64, L, D) contiguous.
#define LSEQ 2048
#define DDIM 64
#define UU   40
#define NBH  64
#define CTX_ELEMS (NBH*UU*DDIM)   // 163840

// ---------------- K12: fused QK_sample + M, 16-lanes-per-l geometry ----------------
__global__ __launch_bounds__(256, 8) void k12_sample_m(
    const float* __restrict__ q, const float* __restrict__ k,
    const int* __restrict__ idxs, float* __restrict__ M) {
  int b = blockIdx.x;
  int bh = b & 63;
  int ltile = b >> 6;
  int t = threadIdx.x;
  int lid = t >> 4;
  int lane = t & 15;
  int l = ltile * 16 + lid;

  float4 qv = *(const float4*)(q + ((size_t)(bh * LSEQ + l)) * DDIM + lane * 4);
  const float* kbase = k + (size_t)bh * LSEQ * DDIM;
  const int4* ir = (const int4*)(idxs + l * UU);

  float mx = -INFINITY, sm = 0.f;
#pragma unroll 1
  for (int s4 = 0; s4 < UU / 4; ++s4) {
    int4 jv = ir[s4];
    float4 k0 = *(const float4*)(kbase + (size_t)jv.x * DDIM + lane * 4);
    float4 k1 = *(const float4*)(kbase + (size_t)jv.y * DDIM + lane * 4);
    float4 k2 = *(const float4*)(kbase + (size_t)jv.z * DDIM + lane * 4);
    float4 k3 = *(const float4*)(kbase + (size_t)jv.w * DDIM + lane * 4);
    float d0 = qv.x * k0.x + qv.y * k0.y + qv.z * k0.z + qv.w * k0.w;
    float d1 = qv.x * k1.x + qv.y * k1.y + qv.z * k1.z + qv.w * k1.w;
    float d2 = qv.x * k2.x + qv.y * k2.y + qv.z * k2.z + qv.w * k2.w;
    float d3 = qv.x * k3.x + qv.y * k3.y + qv.z * k3.z + qv.w * k3.w;
#pragma unroll
    for (int off = 1; off < 16; off <<= 1) {
      d0 += __shfl_xor(d0, off, 64);
      d1 += __shfl_xor(d1, off, 64);
      d2 += __shfl_xor(d2, off, 64);
      d3 += __shfl_xor(d3, off, 64);
    }
    mx = fmaxf(fmaxf(fmaxf(mx, d0), fmaxf(d1, d2)), d3);
    sm += (d0 + d1) + (d2 + d3);
  }
  if (lane == 0) M[bh * LSEQ + l] = mx - sm * (1.0f / (float)LSEQ);
}

// ---------------- K3: top-40 per head; M in regs, shfl + LDS reduce ----------------
__global__ __launch_bounds__(256) void k3_topk(const float* __restrict__ M,
                                               int* __restrict__ Mtop) {
  int bh = blockIdx.x;
  int t = threadIdx.x;
  int w = t >> 6;
  int lane = t & 63;
  float v[8];
#pragma unroll
  for (int j = 0; j < 8; ++j) v[j] = M[bh * LSEQ + t + 256 * j];
  __shared__ float swv[4];
  __shared__ int   swi[4];
  __shared__ int   win;
  for (int it = 0; it < UU; ++it) {
    float bv = -INFINITY; int bi = 0x7fffffff;
#pragma unroll
    for (int j = 0; j < 8; ++j) {
      if (v[j] > bv) { bv = v[j]; bi = t + 256 * j; }
    }
#pragma unroll
    for (int off = 32; off > 0; off >>= 1) {
      float ov = __shfl_xor(bv, off, 64);
      int   oi = __shfl_xor(bi, off, 64);
      if (ov > bv || (ov == bv && oi < bi)) { bv = ov; bi = oi; }
    }
    if (lane == 0) { swv[w] = bv; swi[w] = bi; }
    __syncthreads();
    if (t == 0) {
      float fv = swv[0]; int fi = swi[0];
#pragma unroll
      for (int j = 1; j < 4; ++j) {
        if (swv[j] > fv || (swv[j] == fv && swi[j] < fi)) { fv = swv[j]; fi = swi[j]; }
      }
      Mtop[bh * UU + it] = fi;
      win = fi;
    }
    __syncthreads();
    int wi = win;
    if ((wi & 255) == t) v[wi >> 8] = -INFINITY;
  }
}

// ---------------- K457: fused scores + softmax + attn-write + context ----------------
// 320 blocks: bh = b&63 (XCD-local per head), ug = b>>6 covers u0=ug*8 .. +8.
// Scores kept transposed in LDS sct[l][u] (stride 8). Wave w owns l-quarter.
// 16 lanes per l: coalesced k/v float4 loads, shfl-butterfly dot reduce.
__global__ __launch_bounds__(256, 2) void k457_fused(
    const float* __restrict__ q, const float* __restrict__ k,
    const float* __restrict__ v, const int* __restrict__ Mtop,
    float* __restrict__ attn, float* __restrict__ ctx) {
  __shared__ float sct[LSEQ * 8];      // 64 KB, [l][u]
  __shared__ float red[32 * 64];       // 8 KB
  __shared__ float stats[8];
  int b = blockIdx.x;
  int bh = b & 63;
  int ug = b >> 6;                     // 0..4
  int u0 = ug * 8;
  int t = threadIdx.x;
  int w = t >> 6, lane = t & 63, g = lane >> 4, sub = lane & 15;

  float4 qv[8];
#pragma unroll
  for (int u = 0; u < 8; ++u) {
    int qi = Mtop[bh * UU + u0 + u];
    qv[u] = *(const float4*)(q + ((size_t)(bh * LSEQ) + qi) * DDIM + sub * 4);
  }

  // Phase A: scores -> sct
  const float* kb = k + (size_t)bh * LSEQ * DDIM;
  int lbase = w * 512 + g;
#pragma unroll 1
  for (int i = 0; i < 128; ++i) {
    int l = lbase + i * 4;
    float4 kv = *(const float4*)(kb + (size_t)l * DDIM + sub * 4);
    float d[8];
#pragma unroll
    for (int u = 0; u < 8; ++u) {
      float s = qv[u].x * kv.x + qv[u].y * kv.y + qv[u].z * kv.z + qv[u].w * kv.w;
#pragma unroll
      for (int off = 1; off < 16; off <<= 1) s += __shfl_xor(s, off, 64);
      d[u] = s * 0.125f;
    }
    if (sub == 0) {
      *(float4*)&sct[l * 8]     = make_float4(d[0], d[1], d[2], d[3]);
      *(float4*)&sct[l * 8 + 4] = make_float4(d[4], d[5], d[6], d[7]);
    }
  }
  __syncthreads();

  // Phase B: row max, exp in place, row sum
  float4 ma = make_float4(-INFINITY, -INFINITY, -INFINITY, -INFINITY);
  float4 mb = ma;
#pragma unroll
  for (int i = 0; i < 8; ++i) {
    int l = t + 256 * i;
    float4 a = *(float4*)&sct[l * 8];
    float4 bb = *(float4*)&sct[l * 8 + 4];
    ma.x = fmaxf(ma.x, a.x);  ma.y = fmaxf(ma.y, a.y);
    ma.z = fmaxf(ma.z, a.z);  ma.w = fmaxf(ma.w, a.w);
    mb.x = fmaxf(mb.x, bb.x); mb.y = fmaxf(mb.y, bb.y);
    mb.z = fmaxf(mb.z, bb.z); mb.w = fmaxf(mb.w, bb.w);
  }
#pragma unroll
  for (int off = 32; off > 0; off >>= 1) {
    ma.x = fmaxf(ma.x, __shfl_xor(ma.x, off, 64));
    ma.y = fmaxf(ma.y, __shfl_xor(ma.y, off, 64));
    ma.z = fmaxf(ma.z, __shfl_xor(ma.z, off, 64));
    ma.w = fmaxf(ma.w, __shfl_xor(ma.w, off, 64));
    mb.x = fmaxf(mb.x, __shfl_xor(mb.x, off, 64));
    mb.y = fmaxf(mb.y, __shfl_xor(mb.y, off, 64));
    mb.z = fmaxf(mb.z, __shfl_xor(mb.z, off, 64));
    mb.w = fmaxf(mb.w, __shfl_xor(mb.w, off, 64));
  }
  if (lane == 0) { *(float4*)&red[w * 8] = ma; *(float4*)&red[w * 8 + 4] = mb; }
  __syncthreads();
  {
    float4 r0 = *(float4*)&red[0],  r1 = *(float4*)&red[8];
    float4 r2 = *(float4*)&red[16], r3 = *(float4*)&red[24];
    ma.x = fmaxf(fmaxf(r0.x, r1.x), fmaxf(r2.x, r3.x));
    ma.y = fmaxf(fmaxf(r0.y, r1.y), fmaxf(r2.y, r3.y));
    ma.z = fmaxf(fmaxf(r0.z, r1.z), fmaxf(r2.z, r3.z));
    ma.w = fmaxf(fmaxf(r0.w, r1.w), fmaxf(r2.w, r3.w));
    r0 = *(float4*)&red[4];  r1 = *(float4*)&red[12];
    r2 = *(float4*)&red[20]; r3 = *(float4*)&red[28];
    mb.x = fmaxf(fmaxf(r0.x, r1.x), fmaxf(r2.x, r3.x));
    mb.y = fmaxf(fmaxf(r0.y, r1.y), fmaxf(r2.y, r3.y));
    mb.z = fmaxf(fmaxf(r0.z, r1.z), fmaxf(r2.z, r3.z));
    mb.w = fmaxf(fmaxf(r0.w, r1.w), fmaxf(r2.w, r3.w));
  }
  float4 sa = make_float4(0.f, 0.f, 0.f, 0.f), sb = sa;
#pragma unroll
  for (int i = 0; i < 8; ++i) {
    int l = t + 256 * i;
    float4 a = *(float4*)&sct[l * 8];
    float4 bb = *(float4*)&sct[l * 8 + 4];
    a.x = __expf(a.x - ma.x);  a.y = __expf(a.y - ma.y);
    a.z = __expf(a.z - ma.z);  a.w = __expf(a.w - ma.w);
    bb.x = __expf(bb.x - mb.x); bb.y = __expf(bb.y - mb.y);
    bb.z = __expf(bb.z - mb.z); bb.w = __expf(bb.w - mb.w);
    *(float4*)&sct[l * 8]     = a;
    *(float4*)&sct[l * 8 + 4] = bb;
    sa.x += a.x; sa.y += a.y; sa.z += a.z; sa.w += a.w;
    sb.x += bb.x; sb.y += bb.y; sb.z += bb.z; sb.w += bb.w;
  }
#pragma unroll
  for (int off = 32; off > 0; off >>= 1) {
    sa.x += __shfl_xor(sa.x, off, 64); sa.y += __shfl_xor(sa.y, off, 64);
    sa.z += __shfl_xor(sa.z, off, 64); sa.w += __shfl_xor(sa.w, off, 64);
    sb.x += __shfl_xor(sb.x, off, 64); sb.y += __shfl_xor(sb.y, off, 64);
    sb.z += __shfl_xor(sb.z, off, 64); sb.w += __shfl_xor(sb.w, off, 64);
  }
  if (lane == 0) { *(float4*)&red[64 + w * 8] = sa; *(float4*)&red[64 + w * 8 + 4] = sb; }
  __syncthreads();
  float4 inva, invb;
  {
    float4 r0 = *(float4*)&red[64],  r1 = *(float4*)&red[72];
    float4 r2 = *(float4*)&red[80], r3 = *(float4*)&red[88];
    inva.x = 1.0f / (r0.x + r1.x + r2.x + r3.x);
    inva.y = 1.0f / (r0.y + r1.y + r2.y + r3.y);
    inva.z = 1.0f / (r0.z + r1.z + r2.z + r3.z);
    inva.w = 1.0f / (r0.w + r1.w + r2.w + r3.w);
    r0 = *(float4*)&red[68];  r1 = *(float4*)&red[76];
    r2 = *(float4*)&red[84]; r3 = *(float4*)&red[92];
    invb.x = 1.0f / (r0.x + r1.x + r2.x + r3.x);
    invb.y = 1.0f / (r0.y + r1.y + r2.y + r3.y);
    invb.z = 1.0f / (r0.z + r1.z + r2.z + r3.z);
    invb.w = 1.0f / (r0.w + r1.w + r2.w + r3.w);
  }
  if (t == 0) {
    stats[0] = inva.x; stats[1] = inva.y; stats[2] = inva.z; stats[3] = inva.w;
    stats[4] = invb.x; stats[5] = invb.y; stats[6] = invb.z; stats[7] = invb.w;
  }

  // attn write (normalized)
  float* ap0 = attn + (size_t)(bh * UU + u0) * LSEQ;
#pragma unroll
  for (int i = 0; i < 8; ++i) {
    int l = t + 256 * i;
    float4 a = *(float4*)&sct[l * 8];
    float4 bb = *(float4*)&sct[l * 8 + 4];
    ap0[0 * LSEQ + l] = a.x * inva.x;
    ap0[1 * LSEQ + l] = a.y * inva.y;
    ap0[2 * LSEQ + l] = a.z * inva.z;
    ap0[3 * LSEQ + l] = a.w * inva.w;
    ap0[4 * LSEQ + l] = bb.x * invb.x;
    ap0[5 * LSEQ + l] = bb.y * invb.y;
    ap0[6 * LSEQ + l] = bb.z * invb.z;
    ap0[7 * LSEQ + l] = bb.w * invb.w;
  }
  __syncthreads();   // red about to be reused by phase C

  // Phase C: context
  const float* vb = v + (size_t)bh * LSEQ * DDIM;
  float4 acc[8];
#pragma unroll
  for (int u = 0; u < 8; ++u) acc[u] = make_float4(0.f, 0.f, 0.f, 0.f);
#pragma unroll 1
  for (int i = 0; i < 128; ++i) {
    int l = lbase + i * 4;
    float4 vv = *(const float4*)(vb + (size_t)l * DDIM + sub * 4);
    float4 pa = *(float4*)&sct[l * 8];
    float4 pb = *(float4*)&sct[l * 8 + 4];
    float p[8] = {pa.x, pa.y, pa.z, pa.w, pb.x, pb.y, pb.z, pb.w};
#pragma unroll
    for (int u = 0; u < 8; ++u) {
      acc[u].x = fmaf(p[u], vv.x, acc[u].x);
      acc[u].y = fmaf(p[u], vv.y, acc[u].y);
      acc[u].z = fmaf(p[u], vv.z, acc[u].z);
      acc[u].w = fmaf(p[u], vv.w, acc[u].w);
    }
  }
#pragma unroll
  for (int off = 16; off <= 32; off <<= 1) {
#pragma unroll
    for (int u = 0; u < 8; ++u) {
      acc[u].x += __shfl_xor(acc[u].x, off, 64);
      acc[u].y += __shfl_xor(acc[u].y, off, 64);
      acc[u].z += __shfl_xor(acc[u].z, off, 64);
      acc[u].w += __shfl_xor(acc[u].w, off, 64);
    }
  }
  if (g == 0) {
#pragma unroll
    for (int u = 0; u < 8; ++u)
      *(float4*)&red[(w * 8 + u) * 64 + sub * 4] = acc[u];
  }
  __syncthreads();
  {
    int d = lane;
#pragma unroll
    for (int j = 0; j < 2; ++j) {
      int u = (t >> 6) + j * 4;
      float s = red[(0 * 8 + u) * 64 + d] + red[(1 * 8 + u) * 64 + d] +
                red[(2 * 8 + u) * 64 + d] + red[(3 * 8 + u) * 64 + d];
      ctx[(size_t)(bh * UU + u0 + u) * DDIM + d] = s * stats[u];
    }
  }
}

extern "C" void kernel_launch(void* const* d_in, const int* in_sizes, int n_in,
                              void* d_out, int out_size, void* d_ws, size_t ws_size,
                              hipStream_t stream) {
  const float* q   = (const float*)d_in[0];
  const float* k   = (const float*)d_in[1];
  const float* v   = (const float*)d_in[2];
  const int*   idx = (const int*)d_in[3];

  float* ctx  = (float*)d_out;                  // [NBH, UU, DDIM]
  float* attn = (float*)d_out + CTX_ELEMS;      // [NBH, UU, LSEQ]

  float* M    = (float*)d_ws;                                    // 131072 f
  int*   Mtop = (int*)(M + NBH * LSEQ);                          // 2560 i

  k12_sample_m<<<NBH * 128, 256, 0, stream>>>(q, k, idx, M);
  k3_topk<<<NBH, 256, 0, stream>>>(M, Mtop);
  k457_fused<<<NBH * 5, 256, 0, stream>>>(q, k, v, Mtop, attn, ctx);
}

// Round 6
// 303.879 us; speedup vs baseline: 1.2707x; 1.2707x over previous
//
#include <hip/hip_runtime.h>
#include <math.h>

// ProbAttention (Informer ProbSparse) — B=8 L=2048 H=8 D=64 u=40
// q/k/v reshape(B,H,L,D) is a flat reinterpretation -> treat as (BH=64, L, D) contiguous.
#define LSEQ 2048
#define DDIM 64
#define UU   40
#define NBH  64
#define CTX_ELEMS (NBH*UU*DDIM)   // 163840

// ---------------- K12: fused QK_sample + M, 4-lanes-per-l geometry ----------------
// 2048 blocks: bh = b&63, ltile = b>>6 (64 l per block). Thread = (g = t>>2, sub = t&3).
// Lane sub holds d-slice {sub*4 + m*16}: k-row loads are contiguous 64B per 4-lane group
// (16 lines per wave-inst — same as 16-lane geometry) but only 2 shfls per dot and
// 16 FMA/lane (2.2x fewer dynamic inst than R4's 85us version).
__global__ __launch_bounds__(256, 4) void k12_sample_m(
    const float* __restrict__ q, const float* __restrict__ k,
    const int* __restrict__ idxs, float* __restrict__ M) {
  int b = blockIdx.x;
  int bh = b & 63;
  int ltile = b >> 6;
  int t = threadIdx.x;
  int g = t >> 2;
  int sub = t & 3;
  int l = ltile * 64 + g;

  const float4* qr = (const float4*)(q + (size_t)(bh * LSEQ + l) * DDIM);
  float4 qv[4];
#pragma unroll
  for (int m = 0; m < 4; ++m) qv[m] = qr[4 * m + sub];

  const float* kbase = k + (size_t)bh * LSEQ * DDIM;
  const int4* ir = (const int4*)(idxs + l * UU);

  float mx = -INFINITY, sm = 0.f;
#pragma unroll 1
  for (int s4 = 0; s4 < UU / 4; ++s4) {
    int4 jv = ir[s4];
    const float4* k0 = (const float4*)(kbase + (size_t)jv.x * DDIM);
    const float4* k1 = (const float4*)(kbase + (size_t)jv.y * DDIM);
    const float4* k2 = (const float4*)(kbase + (size_t)jv.z * DDIM);
    const float4* k3 = (const float4*)(kbase + (size_t)jv.w * DDIM);
    float d0 = 0.f, d1 = 0.f, d2 = 0.f, d3 = 0.f;
#pragma unroll
    for (int m = 0; m < 4; ++m) {
      float4 a = k0[4 * m + sub];
      float4 x = qv[m];
      d0 += x.x * a.x + x.y * a.y + x.z * a.z + x.w * a.w;
    }
#pragma unroll
    for (int m = 0; m < 4; ++m) {
      float4 a = k1[4 * m + sub];
      float4 x = qv[m];
      d1 += x.x * a.x + x.y * a.y + x.z * a.z + x.w * a.w;
    }
#pragma unroll
    for (int m = 0; m < 4; ++m) {
      float4 a = k2[4 * m + sub];
      float4 x = qv[m];
      d2 += x.x * a.x + x.y * a.y + x.z * a.z + x.w * a.w;
    }
#pragma unroll
    for (int m = 0; m < 4; ++m) {
      float4 a = k3[4 * m + sub];
      float4 x = qv[m];
      d3 += x.x * a.x + x.y * a.y + x.z * a.z + x.w * a.w;
    }
    d0 += __shfl_xor(d0, 1, 64); d0 += __shfl_xor(d0, 2, 64);
    d1 += __shfl_xor(d1, 1, 64); d1 += __shfl_xor(d1, 2, 64);
    d2 += __shfl_xor(d2, 1, 64); d2 += __shfl_xor(d2, 2, 64);
    d3 += __shfl_xor(d3, 1, 64); d3 += __shfl_xor(d3, 2, 64);
    mx = fmaxf(fmaxf(fmaxf(mx, d0), fmaxf(d1, d2)), d3);
    sm += (d0 + d1) + (d2 + d3);
  }
  if (sub == 0) M[bh * LSEQ + l] = mx - sm * (1.0f / (float)LSEQ);
}

// ---------------- K3: top-40 per head; M in regs, shfl + LDS reduce ----------------
// desc value, tie -> smaller index (matches jax.lax.top_k stability)
__global__ __launch_bounds__(256) void k3_topk(const float* __restrict__ M,
                                               int* __restrict__ Mtop) {
  int bh = blockIdx.x;
  int t = threadIdx.x;
  int w = t >> 6;
  int lane = t & 63;
  float v[8];
#pragma unroll
  for (int j = 0; j < 8; ++j) v[j] = M[bh * LSEQ + t + 256 * j];
  __shared__ float swv[4];
  __shared__ int   swi[4];
  __shared__ int   win;
  for (int it = 0; it < UU; ++it) {
    float bv = -INFINITY; int bi = 0x7fffffff;
#pragma unroll
    for (int j = 0; j < 8; ++j) {
      if (v[j] > bv) { bv = v[j]; bi = t + 256 * j; }
    }
#pragma unroll
    for (int off = 32; off > 0; off >>= 1) {
      float ov = __shfl_xor(bv, off, 64);
      int   oi = __shfl_xor(bi, off, 64);
      if (ov > bv || (ov == bv && oi < bi)) { bv = ov; bi = oi; }
    }
    if (lane == 0) { swv[w] = bv; swi[w] = bi; }
    __syncthreads();
    if (t == 0) {
      float fv = swv[0]; int fi = swi[0];
#pragma unroll
      for (int j = 1; j < 4; ++j) {
        if (swv[j] > fv || (swv[j] == fv && swi[j] < fi)) { fv = swv[j]; fi = swi[j]; }
      }
      Mtop[bh * UU + it] = fi;
      win = fi;
    }
    __syncthreads();
    int wi = win;
    if ((wi & 255) == t) v[wi >> 8] = -INFINITY;
  }
}

// ---------------- K45: fused scores + softmax -> normalized attn ----------------
// 640 blocks: bh = b&63, ug = b>>6 (4 u each). 32KB LDS -> 4 blocks/CU capacity.
// Scores via 4-lanes-per-l geometry (q slices in regs, coalesced k loads, 2 shfls).
// Softmax: wave w owns row u=w (full 2048 in LDS, pure shfl reduce).
// Also zeroes ctx (640*256 == CTX_ELEMS exactly) for k7's atomics.
__global__ __launch_bounds__(256, 4) void k45_scores_softmax(
    const float* __restrict__ q, const float* __restrict__ k,
    const int* __restrict__ Mtop, float* __restrict__ attn,
    float* __restrict__ ctx) {
  __shared__ float sct[4 * LSEQ];    // 32KB, [u][l]
  int b = blockIdx.x;
  int bh = b & 63;
  int u0 = (b >> 6) * 4;
  int t = threadIdx.x;
  int g = t >> 2;
  int sub = t & 3;

  ctx[b * 256 + t] = 0.f;

  float4 qv[4][4];
#pragma unroll
  for (int u = 0; u < 4; ++u) {
    int qi = Mtop[bh * UU + u0 + u];
    const float4* qr = (const float4*)(q + (size_t)(bh * LSEQ + qi) * DDIM);
#pragma unroll
    for (int m = 0; m < 4; ++m) qv[u][m] = qr[4 * m + sub];
  }

  const float* kb = k + (size_t)bh * LSEQ * DDIM;
#pragma unroll 1
  for (int p = 0; p < 32; ++p) {
    int l = p * 64 + g;
    const float4* kr = (const float4*)(kb + (size_t)l * DDIM);
    float4 ks[4];
#pragma unroll
    for (int m = 0; m < 4; ++m) ks[m] = kr[4 * m + sub];
    float d[4];
#pragma unroll
    for (int u = 0; u < 4; ++u) {
      float s = 0.f;
#pragma unroll
      for (int m = 0; m < 4; ++m) {
        float4 x = qv[u][m], a = ks[m];
        s += x.x * a.x + x.y * a.y + x.z * a.z + x.w * a.w;
      }
      s += __shfl_xor(s, 1, 64);
      s += __shfl_xor(s, 2, 64);
      d[u] = s * 0.125f;
    }
    if (sub == 0) {
#pragma unroll
      for (int u = 0; u < 4; ++u) sct[u * LSEQ + l] = d[u];
    }
  }
  __syncthreads();

  // softmax: wave w owns row w
  int w = t >> 6, lane = t & 63;
  float* row = sct + w * LSEQ;
  float vv[32];
  float mx = -INFINITY;
#pragma unroll
  for (int j = 0; j < 32; ++j) { vv[j] = row[lane + 64 * j]; mx = fmaxf(mx, vv[j]); }
#pragma unroll
  for (int off = 32; off > 0; off >>= 1) mx = fmaxf(mx, __shfl_xor(mx, off, 64));
  float sm = 0.f;
#pragma unroll
  for (int j = 0; j < 32; ++j) { vv[j] = __expf(vv[j] - mx); sm += vv[j]; }
#pragma unroll
  for (int off = 32; off > 0; off >>= 1) sm += __shfl_xor(sm, off, 64);
  float inv = 1.0f / sm;
  float* ap = attn + (size_t)(bh * UU + u0 + w) * LSEQ;
#pragma unroll
  for (int j = 0; j < 32; ++j) ap[lane + 64 * j] = vv[j] * inv;
}

// ---------------- K7: context[bh,u,d] += sum_l attn[bh,u,l] * v[bh,l,d] ----------------
// 512 blocks: bh = b&63, l-eighth = b>>6 (256 l). v tile staged in 64KB LDS once;
// wave w owns u-group w*10..w*10+10 (attn rows read once per block, broadcast loads).
// fp32 atomicAdd into ctx (zeroed by k45).
__global__ __launch_bounds__(256) void k7_context(
    const float* __restrict__ attn, const float* __restrict__ v,
    float* __restrict__ ctx) {
  __shared__ float vt[256 * DDIM];   // 64KB
  int b = blockIdx.x;
  int bh = b & 63;
  int l0 = (b >> 6) * 256;
  int t = threadIdx.x;

  const float4* src = (const float4*)(v + ((size_t)bh * LSEQ + l0) * DDIM);
  float4* dst = (float4*)vt;
#pragma unroll
  for (int i = 0; i < 16; ++i) dst[t + 256 * i] = src[t + 256 * i];
  __syncthreads();

  int w = t >> 6;
  int d = t & 63;
  const float* ab = attn + ((size_t)bh * UU + w * 10) * LSEQ + l0;
  float acc[10];
#pragma unroll
  for (int u = 0; u < 10; ++u) acc[u] = 0.f;
#pragma unroll 1
  for (int l4 = 0; l4 < 64; ++l4) {
    int l = l4 * 4;
    float4 av[10];
#pragma unroll
    for (int u = 0; u < 10; ++u)
      av[u] = *(const float4*)(ab + (size_t)u * LSEQ + l);   // 64 lanes same addr -> broadcast
#pragma unroll
    for (int i = 0; i < 4; ++i) {
      float vvv = vt[(l + i) * DDIM + d];
#pragma unroll
      for (int u = 0; u < 10; ++u)
        acc[u] = fmaf(((const float*)&av[u])[i], vvv, acc[u]);
    }
  }
#pragma unroll
  for (int u = 0; u < 10; ++u)
    atomicAdd(&ctx[((size_t)bh * UU + w * 10 + u) * DDIM + d], acc[u]);
}

extern "C" void kernel_launch(void* const* d_in, const int* in_sizes, int n_in,
                              void* d_out, int out_size, void* d_ws, size_t ws_size,
                              hipStream_t stream) {
  const float* q   = (const float*)d_in[0];
  const float* k   = (const float*)d_in[1];
  const float* v   = (const float*)d_in[2];
  const int*   idx = (const int*)d_in[3];

  float* ctx  = (float*)d_out;                  // [NBH, UU, DDIM]
  float* attn = (float*)d_out + CTX_ELEMS;      // [NBH, UU, LSEQ]

  float* M    = (float*)d_ws;                                    // 131072 f
  int*   Mtop = (int*)(M + NBH * LSEQ);                          // 2560 i

  k12_sample_m<<<NBH * 32, 256, 0, stream>>>(q, k, idx, M);
  k3_topk<<<NBH, 256, 0, stream>>>(M, Mtop);
  k45_scores_softmax<<<NBH * 10, 256, 0, stream>>>(q, k, Mtop, attn, ctx);
  k7_context<<<NBH * 8, 256, 0, stream>>>(attn, v, ctx);
}